// Round 3
// baseline (2418.160 us; speedup 1.0000x reference)
//
#include <hip/hip_runtime.h>

#define HD 64
#define L2E 1.4426950408889634f
#define TMAX 2048

typedef float v2f __attribute__((ext_vector_type(2)));

__device__ __forceinline__ float fexp2(float x) { return __builtin_amdgcn_exp2f(x); }
__device__ __forceinline__ float frcp(float x)  { return __builtin_amdgcn_rcpf(x); }
__device__ __forceinline__ float fsig(float x)  { return frcp(fexp2(-L2E * x) + 1.f); }
__device__ __forceinline__ float ftanh_fast(float x) {
    return 1.f - 2.f * frcp(fexp2(2.f * L2E * x) + 1.f);
}

// 64-wide dot for all 4 gate rows of one hidden unit, float2 accumulators
// (v_pk_fma_f32 candidate). w2[g][q] holds W[g*64+l][2q..2q+1]; hp = h as float4*.
__device__ __forceinline__ void dot4(const v2f w2[4][32], const float4* __restrict__ hp,
                                     v2f a[4][2]) {
    #pragma unroll
    for (int q = 0; q < 16; ++q) {
        float4 hv = hp[q];
        v2f hlo; hlo.x = hv.x; hlo.y = hv.y;
        v2f hhi; hhi.x = hv.z; hhi.y = hv.w;
        #pragma unroll
        for (int g = 0; g < 4; ++g) {
            a[g][0] += w2[g][2*q]   * hlo;
            a[g][1] += w2[g][2*q+1] * hhi;
        }
    }
}

// One workgroup (192 threads = 3 waves) per batch element.
// Wave 0 (A): layer-0 gates + c/h update, step t = i
// Wave 1 (B): layer-1 input projection xproj(t)=Wih1*y0(t)+b, t = i-1; output head t = i-3
// Wave 2 (C): layer-1 recurrent gates + c/h update, t = i-2
// Each lane owns all 4 gate rows {g*64+l} of hidden unit l -> update is in-lane,
// no shuffles. One barrier per iteration; cross-wave deps are >=1 iter apart
// (double-buffered LDS, parity-disjoint within an iteration).
__launch_bounds__(192, 1)
__global__ void lstm2_kernel(const float* __restrict__ x,     // [B,T]
                             const float* __restrict__ h0in,  // [2,B,HD]
                             const float* __restrict__ c0in,  // [2,B,HD]
                             const float* __restrict__ Wih0,  // [4H,1]
                             const float* __restrict__ Whh0,  // [4H,HD]
                             const float* __restrict__ bih0,
                             const float* __restrict__ bhh0,
                             const float* __restrict__ Wih1,  // [4H,HD]
                             const float* __restrict__ Whh1,  // [4H,HD]
                             const float* __restrict__ bih1,
                             const float* __restrict__ bhh1,
                             const float* __restrict__ Wlin,  // [1,HD]
                             const float* __restrict__ blin,  // [1]
                             float* __restrict__ out,         // [B,T]
                             int B, int T)
{
    const int b    = blockIdx.x;
    const int tid  = threadIdx.x;
    const int wave = tid >> 6;
    const int l    = tid & 63;

    __shared__ float xin[TMAX];          // staged input series for this batch elem
    __shared__ float h0buf[2][HD];
    __shared__ float h1buf[2][HD];
    __shared__ float xbuf[2][4][HD];     // layer-1 input projections (dbuf)

    v2f w2[4][32];                       // 256 VGPRs: this wave's weight rows
    float bias[4] = {0.f, 0.f, 0.f, 0.f};
    float wx0[4]  = {0.f, 0.f, 0.f, 0.f};
    float cst = 0.f, wl = 0.f, blin0 = 0.f;

    if (wave == 0) {
        #pragma unroll
        for (int g = 0; g < 4; ++g) {
            const float4* wp = (const float4*)(Whh0 + (g * HD + l) * HD);
            #pragma unroll
            for (int q = 0; q < 16; ++q) {
                float4 v = wp[q];
                w2[g][2*q].x   = v.x; w2[g][2*q].y   = v.y;
                w2[g][2*q+1].x = v.z; w2[g][2*q+1].y = v.w;
            }
            bias[g] = bih0[g * HD + l] + bhh0[g * HD + l];
            wx0[g]  = Wih0[g * HD + l];
        }
        cst = c0in[b * HD + l];
        h0buf[1][l] = h0in[b * HD + l];
    } else if (wave == 1) {
        #pragma unroll
        for (int g = 0; g < 4; ++g) {
            const float4* wp = (const float4*)(Wih1 + (g * HD + l) * HD);
            #pragma unroll
            for (int q = 0; q < 16; ++q) {
                float4 v = wp[q];
                w2[g][2*q].x   = v.x; w2[g][2*q].y   = v.y;
                w2[g][2*q+1].x = v.z; w2[g][2*q+1].y = v.w;
            }
            bias[g] = bih1[g * HD + l] + bhh1[g * HD + l];
        }
        wl    = Wlin[l];
        blin0 = blin[0];
    } else {
        #pragma unroll
        for (int g = 0; g < 4; ++g) {
            const float4* wp = (const float4*)(Whh1 + (g * HD + l) * HD);
            #pragma unroll
            for (int q = 0; q < 16; ++q) {
                float4 v = wp[q];
                w2[g][2*q].x   = v.x; w2[g][2*q].y   = v.y;
                w2[g][2*q+1].x = v.z; w2[g][2*q+1].y = v.w;
            }
        }
        cst = c0in[B * HD + b * HD + l];
        h1buf[1][l] = h0in[B * HD + b * HD + l];
    }

    {   // stage x[b,:] into LDS (coalesced float4, one-time)
        const float4* xg = (const float4*)(x + b * T);
        float4* xs = (float4*)xin;
        const int n4 = T >> 2;           // T assumed multiple of 4 (harness: 2048)
        for (int idx = tid; idx < n4; idx += 192) xs[idx] = xg[idx];
    }

    for (int i = 0; i <= T + 2; ++i) {
        __syncthreads();

        if (wave == 0) {
            if (i < T) {                                   // layer 0, t = i
                const float xv = xin[i];
                const float4* hp = (const float4*)(h0buf[(i + 1) & 1]);
                v2f a[4][2];
                #pragma unroll
                for (int g = 0; g < 4; ++g) {
                    a[g][0].x = fmaf(wx0[g], xv, bias[g]); a[g][0].y = 0.f;
                    a[g][1].x = 0.f;                        a[g][1].y = 0.f;
                }
                dot4(w2, hp, a);
                float pre[4];
                #pragma unroll
                for (int g = 0; g < 4; ++g)
                    pre[g] = (a[g][0].x + a[g][0].y) + (a[g][1].x + a[g][1].y);
                float si = fsig(pre[0]), sf = fsig(pre[1]);
                float tg = ftanh_fast(pre[2]), so = fsig(pre[3]);
                cst = fmaf(sf, cst, si * tg);
                h0buf[i & 1][l] = so * ftanh_fast(cst);
            }
        } else if (wave == 1) {
            if (i >= 1 && i <= T) {                        // layer-1 xproj, t = i-1
                const float4* yp = (const float4*)(h0buf[(i + 1) & 1]);
                v2f a[4][2];
                #pragma unroll
                for (int g = 0; g < 4; ++g) {
                    a[g][0].x = bias[g]; a[g][0].y = 0.f;
                    a[g][1].x = 0.f;     a[g][1].y = 0.f;
                }
                dot4(w2, yp, a);
                #pragma unroll
                for (int g = 0; g < 4; ++g)
                    xbuf[(i - 1) & 1][g][l] =
                        (a[g][0].x + a[g][0].y) + (a[g][1].x + a[g][1].y);
            }
            if (i >= 3) {                                  // output head, t = i-3
                float hv = h1buf[(i + 1) & 1][l];
                float p  = wl * hv;
                p += __shfl_xor(p, 32, 64);
                p += __shfl_xor(p, 16, 64);
                p += __shfl_xor(p, 8, 64);
                p += __shfl_xor(p, 4, 64);
                p += __shfl_xor(p, 2, 64);
                p += __shfl_xor(p, 1, 64);
                if (l == 0) out[b * T + (i - 3)] = p + blin0;
            }
        } else {
            if (i >= 2 && i <= T + 1) {                    // layer 1 recurrent, t = i-2
                const float4* hp = (const float4*)(h1buf[(i + 1) & 1]);
                v2f a[4][2];
                #pragma unroll
                for (int g = 0; g < 4; ++g) {
                    a[g][0].x = xbuf[i & 1][g][l]; a[g][0].y = 0.f;
                    a[g][1].x = 0.f;               a[g][1].y = 0.f;
                }
                dot4(w2, hp, a);
                float pre[4];
                #pragma unroll
                for (int g = 0; g < 4; ++g)
                    pre[g] = (a[g][0].x + a[g][0].y) + (a[g][1].x + a[g][1].y);
                float si = fsig(pre[0]), sf = fsig(pre[1]);
                float tg = ftanh_fast(pre[2]), so = fsig(pre[3]);
                cst = fmaf(sf, cst, si * tg);
                h1buf[i & 1][l] = so * ftanh_fast(cst);
            }
        }
    }
}

extern "C" void kernel_launch(void* const* d_in, const int* in_sizes, int n_in,
                              void* d_out, int out_size, void* d_ws, size_t ws_size,
                              hipStream_t stream)
{
    const float* x    = (const float*)d_in[0];
    const float* h0   = (const float*)d_in[1];
    const float* c0   = (const float*)d_in[2];
    const float* Wih0 = (const float*)d_in[3];
    const float* Whh0 = (const float*)d_in[4];
    const float* bih0 = (const float*)d_in[5];
    const float* bhh0 = (const float*)d_in[6];
    const float* Wih1 = (const float*)d_in[7];
    const float* Whh1 = (const float*)d_in[8];
    const float* bih1 = (const float*)d_in[9];
    const float* bhh1 = (const float*)d_in[10];
    const float* Wlin = (const float*)d_in[11];
    const float* blin = (const float*)d_in[12];
    float* out = (float*)d_out;

    const int B = in_sizes[1] / (2 * HD);   // h0 is [2,B,HD]
    const int T = in_sizes[0] / B;          // input is [B,T]  (T <= TMAX assumed)

    lstm2_kernel<<<dim3(B), dim3(192), 0, stream>>>(
        x, h0, c0, Wih0, Whh0, bih0, bhh0,
        Wih1, Whh1, bih1, bhh1, Wlin, blin, out, B, T);
}

// Round 4
// 1968.950 us; speedup vs baseline: 1.2281x; 1.2281x over previous
//
#include <hip/hip_runtime.h>

#define HD 64
#define L2E 1.4426950408889634f
#define TMAX 2048

typedef float v2f __attribute__((ext_vector_type(2)));

__device__ __forceinline__ float fexp2(float x) { return __builtin_amdgcn_exp2f(x); }
__device__ __forceinline__ float frcp(float x)  { return __builtin_amdgcn_rcpf(x); }
__device__ __forceinline__ float ftanh_fast(float x) {
    return 1.f - 2.f * frcp(fexp2(2.f * L2E * x) + 1.f);
}

// One workgroup (512 threads = 8 waves) per batch element.
// Quad-gate layout everywhere: lane l -> gate g = l&3, unit u = 16*(wave&3) + (l>>2).
// Waves 0-3 (A): row g*64+u of BOTH Whh0 (layer-0 dot, t=i) and Wih1 (layer-1
//   input projection, t=i-1) — both dots share ONE h0(i-1) broadcast (the fold).
// Waves 4-7 (B): row g*64+u of Whh1 (layer-1 recurrence, t=i-2); wave 4 also
//   computes the output head at t=i-3.
// c/h update is in-wave (3 quad shuffles + cndmask tree); ONE barrier per iter;
// all cross-wave deps are >=1 iteration apart via parity double buffers.
__launch_bounds__(512, 1)
__global__ void lstm2_kernel(const float* __restrict__ x,     // [B,T]
                             const float* __restrict__ h0in,  // [2,B,HD]
                             const float* __restrict__ c0in,  // [2,B,HD]
                             const float* __restrict__ Wih0,  // [4H,1]
                             const float* __restrict__ Whh0,  // [4H,HD]
                             const float* __restrict__ bih0,
                             const float* __restrict__ bhh0,
                             const float* __restrict__ Wih1,  // [4H,HD]
                             const float* __restrict__ Whh1,  // [4H,HD]
                             const float* __restrict__ bih1,
                             const float* __restrict__ bhh1,
                             const float* __restrict__ Wlin,  // [1,HD]
                             const float* __restrict__ blin,  // [1]
                             float* __restrict__ out,         // [B,T]
                             int B, int T)
{
    const int b    = blockIdx.x;
    const int tid  = threadIdx.x;
    const int wave = tid >> 6;
    const int l    = tid & 63;
    const int g    = l & 3;
    const int u    = (wave & 3) * 16 + (l >> 2);
    const int row  = g * HD + u;
    const bool isA = (wave < 4);

    __shared__ float xin[TMAX];
    __shared__ float h0buf[2][HD];
    __shared__ float h1buf[2][HD];
    __shared__ float xbuf[2][4][65];     // [parity][gate][unit], +1 pad

    v2f w0[32];                          // A: Whh0 row   | B: Whh1 row
    v2f w1[32];                          // A: Wih1 row   | B: unused
    float base0 = 0.f, bias1 = 0.f, wx0 = 0.f, cst, wl = 0.f, blin0 = 0.f;

    // branchless activation for own gate: act = c1 + c2 * rcp(exp2(aa*x)+1)
    const float aa = (g == 2) ? 2.f * L2E : -L2E;
    const float c1 = (g == 2) ? 1.f : 0.f;
    const float c2 = (g == 2) ? -2.f : 1.f;

    if (isA) {
        const float4* wp = (const float4*)(Whh0 + row * HD);
        const float4* up = (const float4*)(Wih1 + row * HD);
        #pragma unroll
        for (int q = 0; q < 16; ++q) {
            float4 v = wp[q];
            w0[2*q]   = v2f{v.x, v.y};
            w0[2*q+1] = v2f{v.z, v.w};
            float4 t = up[q];
            w1[2*q]   = v2f{t.x, t.y};
            w1[2*q+1] = v2f{t.z, t.w};
        }
        base0 = bih0[row] + bhh0[row];
        wx0   = Wih0[row];
        bias1 = bih1[row] + bhh1[row];
        cst   = c0in[b * HD + u];
        if (g == 0) h0buf[1][u] = h0in[b * HD + u];
    } else {
        const float4* wp = (const float4*)(Whh1 + row * HD);
        #pragma unroll
        for (int q = 0; q < 16; ++q) {
            float4 v = wp[q];
            w0[2*q]   = v2f{v.x, v.y};
            w0[2*q+1] = v2f{v.z, v.w};
        }
        cst = c0in[B * HD + b * HD + u];
        if (g == 0) h1buf[1][u] = h0in[B * HD + b * HD + u];
        if (wave == 4) { wl = Wlin[l]; blin0 = blin[0]; }
    }

    {   // stage x[b,:] into LDS (one float4 per thread at T=2048)
        const float4* xg = (const float4*)(x + b * T);
        float4* xs = (float4*)xin;
        const int n4 = T >> 2;
        for (int idx = tid; idx < n4; idx += 512) xs[idx] = xg[idx];
    }

    for (int i = 0; i <= T + 2; ++i) {
        __syncthreads();

        if (isA) {
            if (i <= T) {
                const bool doL0 = (i < T);
                const bool doXp = (i >= 1);
                const float xv  = xin[doL0 ? i : (T - 1)];
                const float4* hp = (const float4*)(h0buf[(i + 1) & 1]); // h0(i-1)
                v2f a00 = {0.f,0.f}, a01 = {0.f,0.f};
                v2f a10 = {0.f,0.f}, a11 = {0.f,0.f};
                #pragma unroll
                for (int q = 0; q < 16; ++q) {
                    float4 t = hp[q];
                    v2f lo = {t.x, t.y}, hi = {t.z, t.w};
                    a00 += w0[2*q]   * lo;
                    a01 += w0[2*q+1] * hi;
                    a10 += w1[2*q]   * lo;
                    a11 += w1[2*q+1] * hi;
                }
                if (doXp)   // xproj(t=i-1) = Wih1*h0(i-1) + biases
                    xbuf[(i + 1) & 1][g][u] =
                        bias1 + (a10.x + a10.y) + (a11.x + a11.y);
                if (doL0) { // layer-0 gates + update, t = i
                    float pre = fmaf(wx0, xv, base0)
                              + (a00.x + a00.y) + (a01.x + a01.y);
                    float act = fmaf(c2, frcp(fexp2(pre * aa) + 1.f), c1);
                    float v1 = __shfl_xor(act, 1, 64);
                    float v2 = __shfl_xor(act, 2, 64);
                    float v3 = __shfl_xor(act, 3, 64);
                    const bool b0 = g & 1, b1 = g & 2;
                    float es = b0 ? v1 : act, os = b0 ? act : v1;
                    float eo = b0 ? v3 : v2,  oo = b0 ? v2 : v3;
                    float si = b1 ? eo : es, sf = b1 ? oo : os;
                    float tg = b1 ? es : eo, so = b1 ? os : oo;
                    cst = fmaf(sf, cst, si * tg);
                    float h = so * ftanh_fast(cst);
                    if (g == 0) h0buf[i & 1][u] = h;
                }
            }
        } else {
            if (i >= 2 && i <= T + 1) {            // layer-1 recurrence, t = i-2
                const float4* hp = (const float4*)(h1buf[(i + 1) & 1]); // h1(i-3)
                v2f a00 = {0.f,0.f}, a01 = {0.f,0.f};
                #pragma unroll
                for (int q = 0; q < 16; ++q) {
                    float4 t = hp[q];
                    a00 += w0[2*q]   * v2f{t.x, t.y};
                    a01 += w0[2*q+1] * v2f{t.z, t.w};
                }
                float pre = xbuf[i & 1][g][u]
                          + (a00.x + a00.y) + (a01.x + a01.y);
                float act = fmaf(c2, frcp(fexp2(pre * aa) + 1.f), c1);
                float v1 = __shfl_xor(act, 1, 64);
                float v2 = __shfl_xor(act, 2, 64);
                float v3 = __shfl_xor(act, 3, 64);
                const bool b0 = g & 1, b1 = g & 2;
                float es = b0 ? v1 : act, os = b0 ? act : v1;
                float eo = b0 ? v3 : v2,  oo = b0 ? v2 : v3;
                float si = b1 ? eo : es, sf = b1 ? oo : os;
                float tg = b1 ? es : eo, so = b1 ? os : oo;
                cst = fmaf(sf, cst, si * tg);
                float h = so * ftanh_fast(cst);
                if (g == 0) h1buf[i & 1][u] = h;
            }
            if (wave == 4 && i >= 3) {             // output head, t = i-3
                float hv = h1buf[(i + 1) & 1][l];
                float p  = wl * hv;
                p += __shfl_xor(p, 32, 64);
                p += __shfl_xor(p, 16, 64);
                p += __shfl_xor(p, 8, 64);
                p += __shfl_xor(p, 4, 64);
                p += __shfl_xor(p, 2, 64);
                p += __shfl_xor(p, 1, 64);
                if (l == 0) out[b * T + (i - 3)] = p + blin0;
            }
        }
    }
}

extern "C" void kernel_launch(void* const* d_in, const int* in_sizes, int n_in,
                              void* d_out, int out_size, void* d_ws, size_t ws_size,
                              hipStream_t stream)
{
    const float* x    = (const float*)d_in[0];
    const float* h0   = (const float*)d_in[1];
    const float* c0   = (const float*)d_in[2];
    const float* Wih0 = (const float*)d_in[3];
    const float* Whh0 = (const float*)d_in[4];
    const float* bih0 = (const float*)d_in[5];
    const float* bhh0 = (const float*)d_in[6];
    const float* Wih1 = (const float*)d_in[7];
    const float* Whh1 = (const float*)d_in[8];
    const float* bih1 = (const float*)d_in[9];
    const float* bhh1 = (const float*)d_in[10];
    const float* Wlin = (const float*)d_in[11];
    const float* blin = (const float*)d_in[12];
    float* out = (float*)d_out;

    const int B = in_sizes[1] / (2 * HD);   // h0 is [2,B,HD]
    const int T = in_sizes[0] / B;          // input is [B,T]  (T <= TMAX assumed)

    lstm2_kernel<<<dim3(B), dim3(512), 0, stream>>>(
        x, h0, c0, Wih0, Whh0, bih0, bhh0,
        Wih1, Whh1, bih1, bhh1, Wlin, blin, out, B, T);
}